// Round 10
// baseline (359.929 us; speedup 1.0000x reference)
//
#include <hip/hip_runtime.h>
#include <math.h>

#define EMB_D 64
#define N_EMB_K 1024
#define HW 4096        // 64*64
#define CHW 262144     // 64*4096
#define NPTS 65536     // 16*64*64
#define Q_OFF 1
#define PERP_OFF 4194305
#define ENC_OFF 4194306
#define FRAG_OFF 4096   // floats: bf16-hi W fragments at ws+16KB (128 KB)

// ws layout (floats): [0..1023] c[k]=0.5||W_k||^2 ; [1024..2047] hist(uint) ;
// [2048] loss ; [4096..36863] bf16-hi B-frags (128 KB, chunk-lane order;
// codes [0,512) occupy the first 64 KB, codes [512,1024) the second — halves contiguous)

typedef __attribute__((ext_vector_type(8))) short short8;   // MFMA A/B frag (4 VGPRs)
typedef __attribute__((ext_vector_type(4))) float float4v;  // MFMA C/D frag
typedef __attribute__((ext_vector_type(2))) float f2;
typedef __attribute__((ext_vector_type(4))) float f4;

union S8 { short8 v; unsigned short u[8]; };

__device__ __forceinline__ unsigned short f2bf_rne(float f) {
    unsigned u = __builtin_bit_cast(unsigned, f);
    unsigned r = u + 0x7FFFu + ((u >> 16) & 1u);
    return (unsigned short)(r >> 16);
}
__device__ __forceinline__ float bf2f(unsigned short h) {
    unsigned u = ((unsigned)h) << 16;
    return __builtin_bit_cast(float, u);
}

// 32 blocks x 256: c[k], hist/loss zero, bf16-hi frags.
// chunk = (code>>4)*2 + ks, lane = kg*16 + (code&15); element j <-> d = ks*32+kg*8+j
__global__ __launch_bounds__(256) void vq_prep(const float* __restrict__ W,
                                               float* __restrict__ ws) {
    const int gid = blockIdx.x * 256 + threadIdx.x;   // 0..8191
    {
        const int code = gid >> 3;
        const int seg  = gid & 7;           // ks = seg>>2, kg = seg&3
        const int d0   = seg << 3;
        const float4* wp = (const float4*)(W + (code << 6) + d0);
        const float4 g0 = wp[0], g1 = wp[1];
        const float vv[8] = {g0.x, g0.y, g0.z, g0.w, g1.x, g1.y, g1.z, g1.w};
        S8 hs;
        #pragma unroll
        for (int j = 0; j < 8; ++j) hs.u[j] = f2bf_rne(vv[j]);
        const int chunk = (code >> 4) * 2 + (seg >> 2);
        const int lane  = ((seg & 3) << 4) + (code & 15);
        ((short8*)(ws + FRAG_OFF))[chunk * 64 + lane] = hs.v;
    }
    if (gid < N_EMB_K) {
        const float* wk = W + (gid << 6);
        float s = 0.f;
        #pragma unroll
        for (int d = 0; d < EMB_D; ++d) s = fmaf(wk[d], wk[d], s);
        ws[gid] = 0.5f * s;
        ((unsigned int*)ws)[1024 + gid] = 0u;
        if (gid == 0) ws[2048] = 0.f;
    }
}

// 1024 blocks x 256 thr, 2 blocks/CU (68.3 KB LDS). Block owns 64 points.
// Codebook staged in two 512-code halves; all big stores AFTER the argmin loop
// so no load ever waits behind the store stream. Co-resident block hides drains.
__global__ __launch_bounds__(256, 2) void vq_main(const float* __restrict__ in,
                                                  const float* __restrict__ W,
                                                  float* __restrict__ out,
                                                  float* __restrict__ ws) {
    __shared__ short8 frag_lds[4096];   // 64 KB: one 512-code half
    __shared__ float  c_lds[1024];      // 4 KB: both halves' c
    __shared__ int    s_bk[64];

    const int tid  = threadIdx.x;
    const int lane = tid & 63;
    const int wv   = tid >> 6;
    const int n16  = lane & 15;
    const int quad = lane >> 4;

    const int blk = blockIdx.x;
    const int b   = blk >> 6;              // image (64 blocks per image)
    const int hw0 = (blk & 63) * 64;       // 64 consecutive hw positions

    const short8* fsrc = (const short8*)(ws + FRAG_OFF);

    // ---- stage c (4 KB) + half-0 frags (64 KB) ----
    ((f4*)c_lds)[tid] = ((const f4*)ws)[tid];
    #pragma unroll
    for (int i = 0; i < 16; ++i) frag_lds[i * 256 + tid] = fsrc[i * 256 + tid];

    // ---- x in registers + A-frags (x hi/lo): point p = wv*16+n16, d = quad*8+j (+32) ----
    float qx[16];
    short8 ah0, ah1, al0, al1;
    {
        const float* xp = in + (size_t)b * CHW + hw0 + (wv * 16 + n16);
        S8 h0, h1, l0, l1;
        #pragma unroll
        for (int j = 0; j < 8; ++j) {
            const int d = quad * 8 + j;
            const float v0 = xp[d * HW];
            const float v1 = xp[(d + 32) * HW];
            qx[j]     = v0;
            qx[j + 8] = v1;
            h0.u[j] = f2bf_rne(v0); l0.u[j] = f2bf_rne(v0 - bf2f(h0.u[j]));
            h1.u[j] = f2bf_rne(v1); l1.u[j] = f2bf_rne(v1 - bf2f(h1.u[j]));
        }
        ah0 = h0.v; al0 = l0.v; ah1 = h1.v; al1 = l1.v;
    }

    float bestv[4] = {-3.0e38f, -3.0e38f, -3.0e38f, -3.0e38f};
    int   bestk[4] = {0, 0, 0, 0};

    // ---- two halves: [sync; (re)stage already done/do; sync; 32 LDS-only tiles] ----
    #pragma unroll
    for (int h = 0; h < 2; ++h) {
        if (h) {
            __syncthreads();   // everyone done reading half-0 LDS
            #pragma unroll
            for (int i = 0; i < 16; ++i)
                frag_lds[i * 256 + tid] = fsrc[4096 + i * 256 + tid];
        }
        __syncthreads();       // staged half visible

        #pragma unroll 2
        for (int t = 0; t < 32; ++t) {
            const short8 bh0 = frag_lds[(2 * t) * 64 + lane];
            const short8 bh1 = frag_lds[(2 * t + 1) * 64 + lane];
            const int  code = (h << 9) + (t << 4) + n16;
            const float cv  = c_lds[code];
            float4v acc = {-cv, -cv, -cv, -cv};   // score = x.w - 0.5||w||^2
            acc = __builtin_amdgcn_mfma_f32_16x16x32_bf16(ah0, bh0, acc, 0, 0, 0);
            acc = __builtin_amdgcn_mfma_f32_16x16x32_bf16(ah1, bh1, acc, 0, 0, 0);
            acc = __builtin_amdgcn_mfma_f32_16x16x32_bf16(al0, bh0, acc, 0, 0, 0);
            acc = __builtin_amdgcn_mfma_f32_16x16x32_bf16(al1, bh1, acc, 0, 0, 0);
            #pragma unroll
            for (int r = 0; r < 4; ++r) {
                if (acc[r] > bestv[r]) { bestv[r] = acc[r]; bestk[r] = code; }  // strict > => lowest k
            }
        }
    }

    // ---- reduce across the 16 code-lanes of each row group ----
    #pragma unroll
    for (int off = 1; off < 16; off <<= 1) {
        #pragma unroll
        for (int r = 0; r < 4; ++r) {
            const float ov = __shfl_xor(bestv[r], off, 64);
            const int   oi = __shfl_xor(bestk[r], off, 64);
            if (ov > bestv[r] || (ov == bestv[r] && oi < bestk[r])) {
                bestv[r] = ov; bestk[r] = oi;
            }
        }
    }
    if (n16 == 0) {
        #pragma unroll
        for (int r = 0; r < 4; ++r) s_bk[wv * 16 + quad * 4 + r] = bestk[r];
    }
    __syncthreads();

    // ---- histogram (2 vmem instrs, before the store burst) ----
    if (tid < 64) atomicAdd((unsigned int*)ws + 1024 + s_bk[tid], 1u);

    // ---- quant + exact fp32 loss: W-row gather from L2 (loads BEFORE enc burst) ----
    {
        const int p  = wv * 16 + n16;
        const int bk = s_bk[p];
        const float* wrow = W + (bk << 6);
        float* qbase = out + Q_OFF + (size_t)b * CHW + hw0 + p;
        float lsum = 0.f;
        #pragma unroll
        for (int j = 0; j < 8; ++j) {
            const int d = quad * 8 + j;
            const float q0 = wrow[d];
            const float q1 = wrow[d + 32];
            const float d0 = q0 - qx[j];
            const float d1 = q1 - qx[j + 8];
            lsum = fmaf(d0, d0, lsum);
            lsum = fmaf(d1, d1, lsum);
            qbase[d * HW]        = qx[j] + d0;       // straight-through arithmetic
            qbase[(d + 32) * HW] = qx[j + 8] + d1;
        }
        #pragma unroll
        for (int off = 1; off < 64; off <<= 1) lsum += __shfl_xor(lsum, off, 64);
        if (lane == 0) atomicAdd(ws + 2048, lsum);
    }

    // ---- enc burst: 64 rows, ones embedded in the zero stream; pure stores,
    //      drained at kernel end while the co-resident block computes ----
    {
        float* encrow0 = out + ENC_OFF + (size_t)blk * 65536;
        for (int r = 0; r < 64; ++r) {
            const int bk = s_bk[r];
            float* row = encrow0 + r * 1024;
            if (tid < 255) {
                const int c = 2 + 4 * tid;
                f4 v;
                v.x = (bk == c)     ? 1.0f : 0.0f;
                v.y = (bk == c + 1) ? 1.0f : 0.0f;
                v.z = (bk == c + 2) ? 1.0f : 0.0f;
                v.w = (bk == c + 3) ? 1.0f : 0.0f;
                *(f4*)(row + c) = v;
            } else {
                f2 v0, v1;
                v0.x = (bk == 0)    ? 1.0f : 0.0f;
                v0.y = (bk == 1)    ? 1.0f : 0.0f;
                v1.x = (bk == 1022) ? 1.0f : 0.0f;
                v1.y = (bk == 1023) ? 1.0f : 0.0f;
                *(f2*)(row)        = v0;
                *(f2*)(row + 1022) = v1;
            }
        }
    }
}

__global__ __launch_bounds__(256) void vq_final(const float* __restrict__ ws,
                                                float* __restrict__ out) {
    __shared__ float red[256];
    const int tid = threadIdx.x;
    const unsigned int* hist = (const unsigned int*)ws + 1024;
    float local = 0.f;
    #pragma unroll
    for (int j = 0; j < 4; ++j) {
        const unsigned int cnt = hist[tid + j * 256];
        const float pr = (float)cnt * (1.0f / 65536.0f);
        local += pr * logf(pr + 1e-10f);
    }
    red[tid] = local;
    __syncthreads();
    for (int off = 128; off > 0; off >>= 1) {
        if (tid < off) red[tid] += red[tid + off];
        __syncthreads();
    }
    if (tid == 0) {
        out[PERP_OFF] = expf(-red[0]);
        out[0] = 1.25f * ws[2048] * (1.0f / 4194304.0f);
    }
}

extern "C" void kernel_launch(void* const* d_in, const int* in_sizes, int n_in,
                              void* d_out, int out_size, void* d_ws, size_t ws_size,
                              hipStream_t stream) {
    const float* in = (const float*)d_in[0];   // (16,64,64,64) fp32 NCHW
    const float* W  = (const float*)d_in[1];   // (1024,64) fp32
    float* out = (float*)d_out;                // [loss | quant(4194304) | perp | enc(67108864)]
    float* ws  = (float*)d_ws;

    vq_prep<<<32, 256, 0, stream>>>(W, ws);
    vq_main<<<NPTS / 64, 256, 0, stream>>>(in, W, out, ws);
    vq_final<<<1, 256, 0, stream>>>(ws, out);
}